// Round 8
// baseline (347.346 us; speedup 1.0000x reference)
//
#include <hip/hip_runtime.h>
#include <math.h>

typedef unsigned int uint;
typedef unsigned short ushort;
typedef __attribute__((ext_vector_type(8))) __bf16 bf16x8;
typedef __attribute__((ext_vector_type(4))) float f32x4;

#define HW 16384   // 128*128

// ---------- helpers ----------
__device__ __forceinline__ ushort f2bf(float f) {          // fp32 -> bf16 RNE
    uint u = __float_as_uint(f);
    u += 0x7fffu + ((u >> 16) & 1u);
    return (ushort)(u >> 16);
}
// XCD-affinity swizzle, 512-block grids (one (b,h) row per block).
__device__ __forceinline__ void bhmap(int& b, int& h) {
    int lin = blockIdx.y * (int)gridDim.x + blockIdx.x;
    int n = (lin & 7) * 64 + (lin >> 3);
    h = n & 127;
    b = n >> 7;
}
// XCD-affinity swizzle, 1024-block grids (half-row per block).
__device__ __forceinline__ void bhmap2(int& b, int& h, int& px0) {
    int lin = blockIdx.x;
    int n = ((lin & 7) << 7) | (lin >> 3);
    b = n >> 8;
    int rm = n & 255;
    h = rm >> 1;
    px0 = (rm & 1) << 6;
}
// swizzled element index into a [rows][128] bf16 LDS tile.
__device__ __forceinline__ int swz(int row, int chunk) {
    return row * 128 + ((chunk ^ (row & 15)) << 3);
}
// bilinear blend of 4 packed bf16 pairs -> packed bf16 pair
__device__ __forceinline__ uint blend2(uint a, uint b, uint c, uint d,
                                       float w00, float w01, float w10, float w11) {
    float lo = w00 * __uint_as_float(a << 16) + w01 * __uint_as_float(b << 16)
             + w10 * __uint_as_float(c << 16) + w11 * __uint_as_float(d << 16);
    float hi = w00 * __uint_as_float(a & 0xffff0000u) + w01 * __uint_as_float(b & 0xffff0000u)
             + w10 * __uint_as_float(c & 0xffff0000u) + w11 * __uint_as_float(d & 0xffff0000u);
    uint ul = __float_as_uint(lo); ul += 0x7fffu + ((ul >> 16) & 1u);
    uint uh = __float_as_uint(hi); uh += 0x7fffu + ((uh >> 16) & 1u);
    return (ul >> 16) | ((uh >> 16) << 16);
}

// ---------------------------------------------------------------------------
// Prep 1: weights -> bf16 [tap][oc][ci]; w_om -> [tap][32(pad)][128] + U-col table
// ---------------------------------------------------------------------------
__global__ __launch_bounds__(256) void prep_w(
    const float* __restrict__ wd, const float* __restrict__ w1,
    const float* __restrict__ w2, const float* __restrict__ wom,
    ushort* __restrict__ wdt, ushort* __restrict__ w1t,
    ushort* __restrict__ w2t, ushort* __restrict__ womt,
    float* __restrict__ womu)
{
    int i = blockIdx.x * 256 + threadIdx.x;
    if (i < 147456) {                       // [k][oc][ci], 9*128*128
        int k = i >> 14, oc = (i >> 7) & 127, ci = i & 127;
        int s = (oc * 128 + ci) * 9 + k;
        wdt[i] = f2bf(wd[s]);
        w1t[i] = f2bf(w1[s]);
        w2t[i] = f2bf(w2[s]);
    }
    if (i < 36864) {                        // [k][32][128]
        int k = i >> 12, oc = (i >> 7) & 31, ci = i & 127;
        womt[i] = (oc < 27) ? f2bf(wom[(oc * 129 + ci) * 9 + k]) : (ushort)0;
    }
    if (i < 288) {                          // U-channel column: [k][32]
        int k = i >> 5, oc = i & 31;
        womu[i] = (oc < 27) ? wom[(oc * 129 + 128) * 9 + k] : 0.f;
    }
}

// ---------------------------------------------------------------------------
// Prep 2: x NCHW fp32 -> x_t NHWC bf16, LDS-transposed per (b,h) row.
// ---------------------------------------------------------------------------
__global__ __launch_bounds__(256) void prep_xt(
    const float* __restrict__ x, ushort* __restrict__ xt)
{
    int b, h; bhmap(b, h);
    const int tid = threadIdx.x;
    __shared__ __align__(16) ushort T[128 * 136];   // [w][c], pad 8
    const int w0 = tid & 127, cg = tid >> 7;
#pragma unroll 4
    for (int it = 0; it < 64; it++) {
        int c = it * 2 + cg;
        float f = x[((size_t)(b * 128 + c)) * HW + h * 128 + w0];
        T[w0 * 136 + c] = f2bf(f);
    }
    __syncthreads();
    const int w1 = tid >> 1, half = tid & 1;
    uint4* dst = (uint4*)(xt + (((size_t)b * HW) + h * 128 + w1) * 128 + half * 64);
    const uint4* src = (const uint4*)&T[w1 * 136 + half * 64];
#pragma unroll
    for (int c8 = 0; c8 < 8; c8++) dst[c8] = src[c8];
}

// ---------------------------------------------------------------------------
// Halo staging helper: 3 rows x 66 px x 128 ch NHWC bf16 -> LDS (49.5 KB).
// src rows gy = h-1+ky, gx = px0-1+xi, xi in [0,66).
// FIX vs r7: each (row,half) owns 64 ch = 8 uint4 chunks; r7 copied only 4
// (chunks 4..7 / 12..15 left as stale LDS -> inf). Now c < 8.
// ---------------------------------------------------------------------------
__device__ __forceinline__ void stage_halo(
    ushort* Hs, const ushort* __restrict__ src, int b, int h, int px0, int tid, int nthr)
{
    for (int s = tid; s < 396; s += nthr) {
        int r = s >> 1, half = s & 1;
        int ky = r / 66, xi = r - ky * 66;
        int gy = h - 1 + ky, gx = px0 - 1 + xi;
        if ((unsigned)gy < 128u && (unsigned)gx < 128u) {
            const uint4* p = (const uint4*)(src + (((size_t)b * HW) + gy * 128 + gx) * 128 + half * 64);
#pragma unroll
            for (int c = 0; c < 8; c++) *(uint4*)&Hs[swz(r, half * 8 + c)] = p[c];
        } else {
            uint4 zz = {0, 0, 0, 0};
#pragma unroll
            for (int c = 0; c < 8; c++) *(uint4*)&Hs[swz(r, half * 8 + c)] = zz;
        }
    }
}

// ---------------------------------------------------------------------------
// k_om: offset/mask head. Halo-once + B-from-global. 256 thr, 1024 blocks.
// Block: 64 px x 32 oc (27 used). Wave: 16 px x 32 oc.
// ---------------------------------------------------------------------------
__global__ __launch_bounds__(256, 3) void k_om(
    const ushort* __restrict__ xt, const float* __restrict__ U,
    const ushort* __restrict__ womt, const float* __restrict__ womu,
    const float* __restrict__ bom, float* __restrict__ omt)
{
    int b, h, px0; bhmap2(b, h, px0);
    const int tid = threadIdx.x;
    const int wid = tid >> 6, lane = tid & 63, lq = lane & 15, quad = lane >> 4;

    __shared__ __align__(16) ushort Hs[198 * 128];   // 49.5 KB
    __shared__ float U3[3 * 66];
    __shared__ float wu[288];

    stage_halo(Hs, xt, b, h, px0, tid, 256);
    for (int s = tid; s < 198; s += 256) {
        int ky = s / 66, xi = s - ky * 66;
        int gy = h - 1 + ky, gx = px0 - 1 + xi;
        float v = 0.f;
        if ((unsigned)gy < 128u && (unsigned)gx < 128u) {
            v = U[(size_t)b * HW + gy * 128 + gx];
            v = fminf(fmaxf(v, 0.f), 1.f);
        }
        U3[s] = v;
    }
    for (int s = tid; s < 288; s += 256) wu[s] = womu[s];
    __syncthreads();

    f32x4 acc[2];
#pragma unroll
    for (int j = 0; j < 2; j++)
#pragma unroll
        for (int r = 0; r < 4; r++) acc[j][r] = 0.f;

#pragma unroll
    for (int ky = 0; ky < 3; ky++)
#pragma unroll
        for (int kx = 0; kx < 3; kx++) {
            const ushort* wt = womt + (ky * 3 + kx) * 4096;
            const int base = ky * 66 + kx + wid * 16;
#pragma unroll
            for (int kk = 0; kk < 4; kk++) {
                int chunk = kk * 4 + quad;
                bf16x8 bv[2];
#pragma unroll
                for (int j = 0; j < 2; j++)
                    bv[j] = *(const bf16x8*)(wt + (j * 16 + lq) * 128 + chunk * 8);
                bf16x8 av = *(const bf16x8*)&Hs[swz(base + lq, chunk)];
#pragma unroll
                for (int j = 0; j < 2; j++)
                    acc[j] = __builtin_amdgcn_mfma_f32_16x16x32_bf16(av, bv[j], acc[j], 0, 0, 0);
            }
        }

    // epilogue: + bias + U-channel conv term; sigmoid for mask channels
#pragma unroll
    for (int j = 0; j < 2; j++) {
        int oc = j * 16 + lq;
        if (oc < 27) {
            float bias = bom[oc];
#pragma unroll
            for (int r = 0; r < 4; r++) {
                int pix = wid * 16 + quad * 4 + r;       // local 0..63
                float v = acc[j][r] + bias;
#pragma unroll
                for (int t = 0; t < 9; t++)
                    v += U3[(t / 3) * 66 + pix + (t % 3)] * wu[t * 32 + oc];
                if (oc >= 18) v = 2.f / (1.f + __expf(-v));
                omt[((size_t)b * HW + h * 128 + px0 + pix) * 32 + oc] = v;
            }
        }
    }
}

// ---------------------------------------------------------------------------
// k_dcn: modulated deformable conv as MFMA GEMM. 512 thr, 8 waves,
// wave tile 64 pix x 32 oc. Corner table double-buffered in LDS; gathers
// 16-lane-contiguous per corner row; B-fragments direct from global (L2).
// ---------------------------------------------------------------------------
__global__ __launch_bounds__(512, 6) void k_dcn(
    const ushort* __restrict__ xt, const float* __restrict__ omt,
    const ushort* __restrict__ wdt, const float* __restrict__ bdcn,
    ushort* __restrict__ zt)
{
    int b, h; bhmap(b, h);
    const int tid = threadIdx.x;
    const int wid = tid >> 6, lane = tid & 63, lq = lane & 15, quad = lane >> 4;
    const int pixbase = (wid & 1) * 64, ocbase = (wid >> 1) * 32;

    __shared__ __align__(16) ushort As[128 * 128];   // 32 KB
    __shared__ __align__(16) int tbl[2][128][8];     // 8 KB

    const int sc = lane & 15;        // channel chunk
    const int sp = lane >> 4;        // pixel slot

    f32x4 acc[4][2];
#pragma unroll
    for (int i = 0; i < 4; i++)
#pragma unroll
        for (int j = 0; j < 2; j++)
#pragma unroll
            for (int r = 0; r < 4; r++) acc[i][j][r] = 0.f;

    const float* omrow = omt + ((size_t)b * HW + h * 128) * 32;
    const ushort* xtb = xt + (size_t)b * HW * 128;

    auto build = [&](int k, int buf) {
        if (tid < 128) {
            int p = tid;
            float dyv = omrow[p * 32 + 2 * k];
            float dxv = omrow[p * 32 + 2 * k + 1];
            float m   = omrow[p * 32 + 18 + k];
            float fy = (float)(h + k / 3 - 1) + dyv;
            float fx = (float)(p + k % 3 - 1) + dxv;
            float y0f = floorf(fy), x0f = floorf(fx);
            float ly = fy - y0f, lx = fx - x0f;
            float hy = 1.f - ly, hx = 1.f - lx;
            bool vy0 = (y0f >= 0.f) && (y0f <= 127.f);
            bool vy1 = (y0f >= -1.f) && (y0f <= 126.f);
            bool vx0 = (x0f >= 0.f) && (x0f <= 127.f);
            bool vx1 = (x0f >= -1.f) && (x0f <= 126.f);
            float w00 = (vy0 && vx0) ? hy * hx * m : 0.f;
            float w01 = (vy0 && vx1) ? hy * lx * m : 0.f;
            float w10 = (vy1 && vx0) ? ly * hx * m : 0.f;
            float w11 = (vy1 && vx1) ? ly * lx * m : 0.f;
            int iy0 = min(max((int)y0f, 0), 127);
            int iy1 = min(max((int)y0f + 1, 0), 127);
            int ix0 = min(max((int)x0f, 0), 127);
            int ix1 = min(max((int)x0f + 1, 0), 127);
            int* tp = &tbl[buf][p][0];
            tp[0] = (iy0 * 128 + ix0) * 128;
            tp[1] = (iy0 * 128 + ix1) * 128;
            tp[2] = (iy1 * 128 + ix0) * 128;
            tp[3] = (iy1 * 128 + ix1) * 128;
            ((float*)tp)[4] = w00; ((float*)tp)[5] = w01;
            ((float*)tp)[6] = w10; ((float*)tp)[7] = w11;
        }
    };

    build(0, 0);
    __syncthreads();

    for (int k = 0; k < 9; k++) {
        const int buf = k & 1;
        // A: 4 rounds, 4 pixels per wave per round, 16 lanes span one corner row
        const ushort* basep = xtb + sc * 8;
#pragma unroll 2
        for (int r = 0; r < 4; r++) {
            int p = r * 32 + wid * 4 + sp;
            int4 off = *(const int4*)&tbl[buf][p][0];
            f32x4 wv = *(const f32x4*)((const float*)&tbl[buf][p][0] + 4);
            uint4 q00 = *(const uint4*)(basep + off.x);
            uint4 q01 = *(const uint4*)(basep + off.y);
            uint4 q10 = *(const uint4*)(basep + off.z);
            uint4 q11 = *(const uint4*)(basep + off.w);
            uint4 st;
            st.x = blend2(q00.x, q01.x, q10.x, q11.x, wv[0], wv[1], wv[2], wv[3]);
            st.y = blend2(q00.y, q01.y, q10.y, q11.y, wv[0], wv[1], wv[2], wv[3]);
            st.z = blend2(q00.z, q01.z, q10.z, q11.z, wv[0], wv[1], wv[2], wv[3]);
            st.w = blend2(q00.w, q01.w, q10.w, q11.w, wv[0], wv[1], wv[2], wv[3]);
            *(uint4*)&As[swz(p, sc)] = st;
        }
        __syncthreads();
        if (k < 8) build(k + 1, buf ^ 1);      // hides behind MFMA
        const ushort* wt = wdt + (size_t)k * 16384;
#pragma unroll
        for (int kk = 0; kk < 4; kk++) {
            int chunk = kk * 4 + quad;
            bf16x8 av[4], bv[2];
#pragma unroll
            for (int j = 0; j < 2; j++)
                bv[j] = *(const bf16x8*)(wt + (ocbase + j * 16 + lq) * 128 + chunk * 8);
#pragma unroll
            for (int i = 0; i < 4; i++) av[i] = *(const bf16x8*)&As[swz(pixbase + i * 16 + lq, chunk)];
#pragma unroll
            for (int i = 0; i < 4; i++)
#pragma unroll
                for (int j = 0; j < 2; j++)
                    acc[i][j] = __builtin_amdgcn_mfma_f32_16x16x32_bf16(av[i], bv[j], acc[i][j], 0, 0, 0);
        }
        __syncthreads();
    }

    size_t prow = ((size_t)b * HW + h * 128) * 128;
#pragma unroll
    for (int j = 0; j < 2; j++) {
        int oc = ocbase + j * 16 + lq;
        float bias = bdcn[oc];
#pragma unroll
        for (int i = 0; i < 4; i++)
#pragma unroll
            for (int r = 0; r < 4; r++) {
                int pix = pixbase + i * 16 + quad * 4 + r;
                zt[prow + (size_t)pix * 128 + oc] = f2bf(acc[i][j][r] + bias);
            }
    }
}

// ---------------------------------------------------------------------------
// k_conv1: r1 = relu(conv3x3(z) + b1). Halo-once + B-from-global.
// 256 thr, 1024 blocks. Block: 64 px x 128 oc. Wave: 64 px x 32 oc.
// ---------------------------------------------------------------------------
__global__ __launch_bounds__(256, 3) void k_conv1(
    const ushort* __restrict__ zt, const ushort* __restrict__ w1t,
    const float* __restrict__ b1, ushort* __restrict__ r1t)
{
    int b, h, px0; bhmap2(b, h, px0);
    const int tid = threadIdx.x;
    const int wid = tid >> 6, lane = tid & 63, lq = lane & 15, quad = lane >> 4;
    const int ocbase = wid * 32;

    __shared__ __align__(16) ushort Hs[198 * 128];   // 49.5 KB

    stage_halo(Hs, zt, b, h, px0, tid, 256);
    __syncthreads();

    f32x4 acc[4][2];
#pragma unroll
    for (int i = 0; i < 4; i++)
#pragma unroll
        for (int j = 0; j < 2; j++)
#pragma unroll
            for (int r = 0; r < 4; r++) acc[i][j][r] = 0.f;

#pragma unroll
    for (int ky = 0; ky < 3; ky++)
#pragma unroll
        for (int kx = 0; kx < 3; kx++) {
            const ushort* wt = w1t + (size_t)(ky * 3 + kx) * 16384;
            const int base = ky * 66 + kx;
#pragma unroll
            for (int kk = 0; kk < 4; kk++) {
                int chunk = kk * 4 + quad;
                bf16x8 bv[2];
#pragma unroll
                for (int j = 0; j < 2; j++)
                    bv[j] = *(const bf16x8*)(wt + (ocbase + j * 16 + lq) * 128 + chunk * 8);
                bf16x8 av[4];
#pragma unroll
                for (int i = 0; i < 4; i++)
                    av[i] = *(const bf16x8*)&Hs[swz(base + i * 16 + lq, chunk)];
#pragma unroll
                for (int i = 0; i < 4; i++)
#pragma unroll
                    for (int j = 0; j < 2; j++)
                        acc[i][j] = __builtin_amdgcn_mfma_f32_16x16x32_bf16(av[i], bv[j], acc[i][j], 0, 0, 0);
            }
        }

    size_t prow = ((size_t)b * HW + h * 128 + px0) * 128;
#pragma unroll
    for (int j = 0; j < 2; j++) {
        int oc = ocbase + j * 16 + lq;
        float bias = b1[oc];
#pragma unroll
        for (int i = 0; i < 4; i++)
#pragma unroll
            for (int r = 0; r < 4; r++) {
                int pix = i * 16 + quad * 4 + r;
                r1t[prow + (size_t)pix * 128 + oc] = f2bf(fmaxf(acc[i][j][r] + bias, 0.f));
            }
    }
}

// ---------------------------------------------------------------------------
// k_conv2: out = relu(x + (conv3x3(r1)+b2) * sigmoid(10*(clipU-0.5))).
// Halo-once + A(w2)-from-global; M=oc so NCHW fp32 stores coalesce.
// 256 thr, 1024 blocks. Block: 64 px x 128 oc. Wave: 32 oc x 64 px.
// ---------------------------------------------------------------------------
__global__ __launch_bounds__(256, 3) void k_conv2(
    const ushort* __restrict__ r1t, const ushort* __restrict__ w2t,
    const float* __restrict__ b2, const float* __restrict__ x,
    const float* __restrict__ U, float* __restrict__ out)
{
    int b, h, px0; bhmap2(b, h, px0);
    const int tid = threadIdx.x;
    const int wid = tid >> 6, lane = tid & 63, lq = lane & 15, quad = lane >> 4;
    const int ocbase = wid * 32;   // M: oc

    __shared__ __align__(16) ushort Hs[198 * 128];   // 49.5 KB

    stage_halo(Hs, r1t, b, h, px0, tid, 256);
    __syncthreads();

    f32x4 acc[2][4];   // [oc group][pixel group]
#pragma unroll
    for (int i = 0; i < 2; i++)
#pragma unroll
        for (int j = 0; j < 4; j++)
#pragma unroll
            for (int r = 0; r < 4; r++) acc[i][j][r] = 0.f;

#pragma unroll
    for (int ky = 0; ky < 3; ky++)
#pragma unroll
        for (int kx = 0; kx < 3; kx++) {
            const ushort* wt = w2t + (size_t)(ky * 3 + kx) * 16384;
            const int base = ky * 66 + kx;
#pragma unroll
            for (int kk = 0; kk < 4; kk++) {
                int chunk = kk * 4 + quad;
                bf16x8 av[2], bv[4];
#pragma unroll
                for (int i = 0; i < 2; i++)
                    av[i] = *(const bf16x8*)(wt + (ocbase + i * 16 + lq) * 128 + chunk * 8);
#pragma unroll
                for (int j = 0; j < 4; j++)
                    bv[j] = *(const bf16x8*)&Hs[swz(base + j * 16 + lq, chunk)];
#pragma unroll
                for (int i = 0; i < 2; i++)
#pragma unroll
                    for (int j = 0; j < 4; j++)
                        acc[i][j] = __builtin_amdgcn_mfma_f32_16x16x32_bf16(av[i], bv[j], acc[i][j], 0, 0, 0);
            }
        }

#pragma unroll
    for (int j = 0; j < 4; j++) {
        int pix = j * 16 + lq;                       // local 0..63
        float u = U[(size_t)b * HW + h * 128 + px0 + pix];
        u = fminf(fmaxf(u, 0.f), 1.f);
        float g = 1.f / (1.f + __expf(-10.f * (u - 0.5f)));
#pragma unroll
        for (int i = 0; i < 2; i++) {
            f32x4 b4 = *(const f32x4*)&b2[ocbase + i * 16 + quad * 4];
#pragma unroll
            for (int r = 0; r < 4; r++) {
                int oc = ocbase + i * 16 + quad * 4 + r;
                size_t idx = ((size_t)(b * 128 + oc)) * HW + h * 128 + px0 + pix;
                float v = acc[i][j][r] + b4[r];
                out[idx] = fmaxf(x[idx] + v * g, 0.f);
            }
        }
    }
}

// ---------------------------------------------------------------------------
extern "C" void kernel_launch(void* const* d_in, const int* in_sizes, int n_in,
                              void* d_out, int out_size, void* d_ws, size_t ws_size,
                              hipStream_t stream)
{
    const float* x     = (const float*)d_in[0];
    const float* U     = (const float*)d_in[1];
    const float* w_om  = (const float*)d_in[2];
    const float* b_om  = (const float*)d_in[3];
    const float* w_dcn = (const float*)d_in[4];
    const float* b_dcn = (const float*)d_in[5];
    const float* w1    = (const float*)d_in[6];
    const float* b1    = (const float*)d_in[7];
    const float* w2    = (const float*)d_in[8];
    const float* b2    = (const float*)d_in[9];
    float* out = (float*)d_out;

    char* p = (char*)d_ws;
    ushort* xt   = (ushort*)p; p += (size_t)4 * HW * 128 * 2;   // 16.78 MB
    ushort* zt   = (ushort*)p; p += (size_t)4 * HW * 128 * 2;
    ushort* r1t  = (ushort*)p; p += (size_t)4 * HW * 128 * 2;
    float*  omt  = (float*)p;  p += (size_t)4 * HW * 32 * 4;    // 8.39 MB
    ushort* wdt  = (ushort*)p; p += 147456 * 2;
    ushort* w1t  = (ushort*)p; p += 147456 * 2;
    ushort* w2t  = (ushort*)p; p += 147456 * 2;
    ushort* womt = (ushort*)p; p += 36864 * 2;
    float*  womu = (float*)p;  p += 288 * 4;

    prep_w<<<576, 256, 0, stream>>>(w_dcn, w1, w2, w_om, wdt, w1t, w2t, womt, womu);
    prep_xt<<<dim3(128, 4), 256, 0, stream>>>(x, xt);
    k_om<<<1024, 256, 0, stream>>>(xt, U, womt, womu, b_om, omt);
    k_dcn<<<dim3(128, 4), 512, 0, stream>>>(xt, omt, wdt, b_dcn, zt);
    k_conv1<<<1024, 256, 0, stream>>>(zt, w1t, b1, r1t);
    k_conv2<<<1024, 256, 0, stream>>>(r1t, w2t, b2, x, U, out);
}

// Round 9
// 239.616 us; speedup vs baseline: 1.4496x; 1.4496x over previous
//
#include <hip/hip_runtime.h>
#include <math.h>

typedef unsigned int uint;
typedef unsigned short ushort;
typedef __attribute__((ext_vector_type(8))) __bf16 bf16x8;
typedef __attribute__((ext_vector_type(4))) float f32x4;

#define HW 16384   // 128*128

// ---------- helpers ----------
__device__ __forceinline__ ushort f2bf(float f) {          // fp32 -> bf16 RNE
    uint u = __float_as_uint(f);
    u += 0x7fffu + ((u >> 16) & 1u);
    return (ushort)(u >> 16);
}
// XCD-affinity swizzle, 512-block grids (one (b,h) row per block).
__device__ __forceinline__ void bhmap(int& b, int& h) {
    int lin = blockIdx.y * (int)gridDim.x + blockIdx.x;
    int n = (lin & 7) * 64 + (lin >> 3);
    h = n & 127;
    b = n >> 7;
}
// XCD-affinity swizzle, 1024-block grids (half-row per block).
__device__ __forceinline__ void bhmap2(int& b, int& h, int& px0) {
    int lin = blockIdx.x;
    int n = ((lin & 7) << 7) | (lin >> 3);
    b = n >> 8;
    int rm = n & 255;
    h = rm >> 1;
    px0 = (rm & 1) << 6;
}
// swizzled element index into a [rows][128] bf16 LDS tile.
__device__ __forceinline__ int swz(int row, int chunk) {
    return row * 128 + ((chunk ^ (row & 15)) << 3);
}
// bilinear blend of 4 packed bf16 pairs -> packed bf16 pair
__device__ __forceinline__ uint blend2(uint a, uint b, uint c, uint d,
                                       float w00, float w01, float w10, float w11) {
    float lo = w00 * __uint_as_float(a << 16) + w01 * __uint_as_float(b << 16)
             + w10 * __uint_as_float(c << 16) + w11 * __uint_as_float(d << 16);
    float hi = w00 * __uint_as_float(a & 0xffff0000u) + w01 * __uint_as_float(b & 0xffff0000u)
             + w10 * __uint_as_float(c & 0xffff0000u) + w11 * __uint_as_float(d & 0xffff0000u);
    uint ul = __float_as_uint(lo); ul += 0x7fffu + ((ul >> 16) & 1u);
    uint uh = __float_as_uint(hi); uh += 0x7fffu + ((uh >> 16) & 1u);
    return (ul >> 16) | ((uh >> 16) << 16);
}

// ---------------------------------------------------------------------------
// Prep 1: wdt (k_dcn) -> bf16 [tap][oc][ci] (row layout, LDS-staged in k_dcn).
// w1B/w2B/womB (convs/k_om) -> fragment-contiguous layout:
//   idx = ((((tap*G + oc/16)*4 + kk)*4 + quad)*16 + (oc&15))*8 + (ci&7)
//   where chunk=ci/8, kk=chunk/4, quad=chunk&3; G=8 (128 oc) or 2 (32 oc).
//   One wave's fragment (tap, ocg16, kk) = contiguous 1 KB, lane offset 16 B.
// ---------------------------------------------------------------------------
__global__ __launch_bounds__(256) void prep_w(
    const float* __restrict__ wd, const float* __restrict__ w1,
    const float* __restrict__ w2, const float* __restrict__ wom,
    ushort* __restrict__ wdt, ushort* __restrict__ w1B,
    ushort* __restrict__ w2B, ushort* __restrict__ womB,
    float* __restrict__ womu)
{
    int i = blockIdx.x * 256 + threadIdx.x;
    if (i < 147456) {                       // k, oc, ci
        int k = i >> 14, oc = (i >> 7) & 127, ci = i & 127;
        int s = (oc * 128 + ci) * 9 + k;
        wdt[i] = f2bf(wd[s]);               // old row layout for k_dcn
        int chunk = ci >> 3, kk = chunk >> 2, quad = chunk & 3, e = ci & 7;
        int d = ((((k * 8 + (oc >> 4)) * 4 + kk) * 4 + quad) * 16 + (oc & 15)) * 8 + e;
        w1B[d] = f2bf(w1[s]);
        w2B[d] = f2bf(w2[s]);
    }
    if (i < 36864) {                        // k, oc(32 pad), ci
        int k = i >> 12, oc = (i >> 7) & 31, ci = i & 127;
        int chunk = ci >> 3, kk = chunk >> 2, quad = chunk & 3, e = ci & 7;
        int d = ((((k * 2 + (oc >> 4)) * 4 + kk) * 4 + quad) * 16 + (oc & 15)) * 8 + e;
        womB[d] = (oc < 27) ? f2bf(wom[(oc * 129 + ci) * 9 + k]) : (ushort)0;
    }
    if (i < 288) {                          // U-channel column: [k][32]
        int k = i >> 5, oc = i & 31;
        womu[i] = (oc < 27) ? wom[(oc * 129 + 128) * 9 + k] : 0.f;
    }
}

// ---------------------------------------------------------------------------
// Prep 2: x NCHW fp32 -> x_t NHWC bf16, LDS-transposed per (b,h) row.
// ---------------------------------------------------------------------------
__global__ __launch_bounds__(256) void prep_xt(
    const float* __restrict__ x, ushort* __restrict__ xt)
{
    int b, h; bhmap(b, h);
    const int tid = threadIdx.x;
    __shared__ __align__(16) ushort T[128 * 136];   // [w][c], pad 8
    const int w0 = tid & 127, cg = tid >> 7;
#pragma unroll 4
    for (int it = 0; it < 64; it++) {
        int c = it * 2 + cg;
        float f = x[((size_t)(b * 128 + c)) * HW + h * 128 + w0];
        T[w0 * 136 + c] = f2bf(f);
    }
    __syncthreads();
    const int w1 = tid >> 1, half = tid & 1;
    uint4* dst = (uint4*)(xt + (((size_t)b * HW) + h * 128 + w1) * 128 + half * 64);
    const uint4* src = (const uint4*)&T[w1 * 136 + half * 64];
#pragma unroll
    for (int c8 = 0; c8 < 8; c8++) dst[c8] = src[c8];
}

// ---------------------------------------------------------------------------
// Halo staging: 3 rows x 66 px x 128 ch NHWC bf16 -> LDS (49.5 KB).
// ---------------------------------------------------------------------------
__device__ __forceinline__ void stage_halo(
    ushort* Hs, const ushort* __restrict__ src, int b, int h, int px0, int tid, int nthr)
{
    for (int s = tid; s < 396; s += nthr) {
        int r = s >> 1, half = s & 1;
        int ky = r / 66, xi = r - ky * 66;
        int gy = h - 1 + ky, gx = px0 - 1 + xi;
        if ((unsigned)gy < 128u && (unsigned)gx < 128u) {
            const uint4* p = (const uint4*)(src + (((size_t)b * HW) + gy * 128 + gx) * 128 + half * 64);
#pragma unroll
            for (int c = 0; c < 8; c++) *(uint4*)&Hs[swz(r, half * 8 + c)] = p[c];
        } else {
            uint4 zz = {0, 0, 0, 0};
#pragma unroll
            for (int c = 0; c < 8; c++) *(uint4*)&Hs[swz(r, half * 8 + c)] = zz;
        }
    }
}

// ---------------------------------------------------------------------------
// k_om: offset/mask head. Halo-once + register-prefetched B. 256 thr.
// Block: 64 px x 32 oc (27 used). Wave: 16 px x 32 oc.
// ---------------------------------------------------------------------------
__global__ __launch_bounds__(256, 3) void k_om(
    const ushort* __restrict__ xt, const float* __restrict__ U,
    const ushort* __restrict__ womB, const float* __restrict__ womu,
    const float* __restrict__ bom, float* __restrict__ omt)
{
    int b, h, px0; bhmap2(b, h, px0);
    const int tid = threadIdx.x;
    const int wid = tid >> 6, lane = tid & 63, lq = lane & 15, quad = lane >> 4;

    __shared__ __align__(16) ushort Hs[198 * 128];   // 49.5 KB
    __shared__ float U3[3 * 66];
    __shared__ float wu[288];

    stage_halo(Hs, xt, b, h, px0, tid, 256);
    for (int s = tid; s < 198; s += 256) {
        int ky = s / 66, xi = s - ky * 66;
        int gy = h - 1 + ky, gx = px0 - 1 + xi;
        float v = 0.f;
        if ((unsigned)gy < 128u && (unsigned)gx < 128u) {
            v = U[(size_t)b * HW + gy * 128 + gx];
            v = fminf(fmaxf(v, 0.f), 1.f);
        }
        U3[s] = v;
    }
    for (int s = tid; s < 288; s += 256) wu[s] = womu[s];

    f32x4 acc[2];
#pragma unroll
    for (int j = 0; j < 2; j++)
#pragma unroll
        for (int r = 0; r < 4; r++) acc[j][r] = 0.f;

    bf16x8 bcur[2][4], bnext[2][4];
#pragma unroll
    for (int j = 0; j < 2; j++)
#pragma unroll
        for (int kk = 0; kk < 4; kk++)
            bcur[j][kk] = *(const bf16x8*)(womB + (size_t)((j * 4 + kk) * 512) + lane * 8);

    __syncthreads();

#pragma unroll
    for (int t9 = 0; t9 < 9; t9++) {
        if (t9 < 8) {
#pragma unroll
            for (int j = 0; j < 2; j++)
#pragma unroll
                for (int kk = 0; kk < 4; kk++)
                    bnext[j][kk] = *(const bf16x8*)(womB + (size_t)((((t9 + 1) * 2 + j) * 4 + kk) * 512) + lane * 8);
        }
        const int base = (t9 / 3) * 66 + (t9 % 3) + wid * 16;
#pragma unroll
        for (int kk = 0; kk < 4; kk++) {
            int chunk = kk * 4 + quad;
            bf16x8 av = *(const bf16x8*)&Hs[swz(base + lq, chunk)];
#pragma unroll
            for (int j = 0; j < 2; j++)
                acc[j] = __builtin_amdgcn_mfma_f32_16x16x32_bf16(av, bcur[j][kk], acc[j], 0, 0, 0);
        }
#pragma unroll
        for (int j = 0; j < 2; j++)
#pragma unroll
            for (int kk = 0; kk < 4; kk++) bcur[j][kk] = bnext[j][kk];
    }

    // epilogue: + bias + U-channel conv term; sigmoid for mask channels
#pragma unroll
    for (int j = 0; j < 2; j++) {
        int oc = j * 16 + lq;
        if (oc < 27) {
            float bias = bom[oc];
#pragma unroll
            for (int r = 0; r < 4; r++) {
                int pix = wid * 16 + quad * 4 + r;       // local 0..63
                float v = acc[j][r] + bias;
#pragma unroll
                for (int t = 0; t < 9; t++)
                    v += U3[(t / 3) * 66 + pix + (t % 3)] * wu[t * 32 + oc];
                if (oc >= 18) v = 2.f / (1.f + __expf(-v));
                omt[((size_t)b * HW + h * 128 + px0 + pix) * 32 + oc] = v;
            }
        }
    }
}

// ---------------------------------------------------------------------------
// k_dcn: modulated deformable conv as MFMA GEMM (round-6 version, measured
// 58.6 us). 512 thr, 8 waves, wave tile 64 pix x 32 oc. Corner table
// double-buffered in LDS; B staged to LDS per tap.
// ---------------------------------------------------------------------------
__global__ __launch_bounds__(512, 4) void k_dcn(
    const ushort* __restrict__ xt, const float* __restrict__ omt,
    const ushort* __restrict__ wdt, const float* __restrict__ bdcn,
    ushort* __restrict__ zt)
{
    int b, h; bhmap(b, h);
    const int tid = threadIdx.x;
    const int wid = tid >> 6, lane = tid & 63, lq = lane & 15, quad = lane >> 4;
    const int pixbase = (wid & 1) * 64, ocbase = (wid >> 1) * 32;

    __shared__ __align__(16) ushort As[128 * 128];   // 32 KB
    __shared__ __align__(16) ushort Bs[128 * 128];   // 32 KB
    __shared__ __align__(16) int tbl[2][128][8];     // 8 KB

    const int sc = lane & 15;        // channel chunk
    const int sp = lane >> 4;        // pixel slot

    f32x4 acc[4][2];
#pragma unroll
    for (int i = 0; i < 4; i++)
#pragma unroll
        for (int j = 0; j < 2; j++)
#pragma unroll
            for (int r = 0; r < 4; r++) acc[i][j][r] = 0.f;

    const float* omrow = omt + ((size_t)b * HW + h * 128) * 32;
    const ushort* xtb = xt + (size_t)b * HW * 128;

    auto build = [&](int k, int buf) {
        if (tid < 128) {
            int p = tid;
            float dyv = omrow[p * 32 + 2 * k];
            float dxv = omrow[p * 32 + 2 * k + 1];
            float m   = omrow[p * 32 + 18 + k];
            float fy = (float)(h + k / 3 - 1) + dyv;
            float fx = (float)(p + k % 3 - 1) + dxv;
            float y0f = floorf(fy), x0f = floorf(fx);
            float ly = fy - y0f, lx = fx - x0f;
            float hy = 1.f - ly, hx = 1.f - lx;
            bool vy0 = (y0f >= 0.f) && (y0f <= 127.f);
            bool vy1 = (y0f >= -1.f) && (y0f <= 126.f);
            bool vx0 = (x0f >= 0.f) && (x0f <= 127.f);
            bool vx1 = (x0f >= -1.f) && (x0f <= 126.f);
            float w00 = (vy0 && vx0) ? hy * hx * m : 0.f;
            float w01 = (vy0 && vx1) ? hy * lx * m : 0.f;
            float w10 = (vy1 && vx0) ? ly * hx * m : 0.f;
            float w11 = (vy1 && vx1) ? ly * lx * m : 0.f;
            int iy0 = min(max((int)y0f, 0), 127);
            int iy1 = min(max((int)y0f + 1, 0), 127);
            int ix0 = min(max((int)x0f, 0), 127);
            int ix1 = min(max((int)x0f + 1, 0), 127);
            int* tp = &tbl[buf][p][0];
            tp[0] = (iy0 * 128 + ix0) * 128;
            tp[1] = (iy0 * 128 + ix1) * 128;
            tp[2] = (iy1 * 128 + ix0) * 128;
            tp[3] = (iy1 * 128 + ix1) * 128;
            ((float*)tp)[4] = w00; ((float*)tp)[5] = w01;
            ((float*)tp)[6] = w10; ((float*)tp)[7] = w11;
        }
    };

    build(0, 0);
    __syncthreads();

    const int brow = tid >> 2, bq = tid & 3;   // Bs: 4 x 16B per thread
    for (int k = 0; k < 9; k++) {
        const int buf = k & 1;
        {
            const uint4* src = (const uint4*)(wdt + (size_t)k * 16384 + brow * 128 + bq * 32);
#pragma unroll
            for (int c = 0; c < 4; c++) *(uint4*)&Bs[swz(brow, bq * 4 + c)] = src[c];
        }
        // A: 4 rounds, 4 pixels per wave per round, 16 lanes span one corner row
        const ushort* basep = xtb + sc * 8;
#pragma unroll 2
        for (int r = 0; r < 4; r++) {
            int p = r * 32 + wid * 4 + sp;
            int4 off = *(const int4*)&tbl[buf][p][0];
            f32x4 wv = *(const f32x4*)((const float*)&tbl[buf][p][0] + 4);
            uint4 q00 = *(const uint4*)(basep + off.x);
            uint4 q01 = *(const uint4*)(basep + off.y);
            uint4 q10 = *(const uint4*)(basep + off.z);
            uint4 q11 = *(const uint4*)(basep + off.w);
            uint4 st;
            st.x = blend2(q00.x, q01.x, q10.x, q11.x, wv[0], wv[1], wv[2], wv[3]);
            st.y = blend2(q00.y, q01.y, q10.y, q11.y, wv[0], wv[1], wv[2], wv[3]);
            st.z = blend2(q00.z, q01.z, q10.z, q11.z, wv[0], wv[1], wv[2], wv[3]);
            st.w = blend2(q00.w, q01.w, q10.w, q11.w, wv[0], wv[1], wv[2], wv[3]);
            *(uint4*)&As[swz(p, sc)] = st;
        }
        __syncthreads();
        if (k < 8) build(k + 1, buf ^ 1);      // hides behind MFMA
#pragma unroll
        for (int kk = 0; kk < 4; kk++) {
            int chunk = kk * 4 + quad;
            bf16x8 av[4], bv[2];
#pragma unroll
            for (int j = 0; j < 2; j++) bv[j] = *(const bf16x8*)&Bs[swz(ocbase + j * 16 + lq, chunk)];
#pragma unroll
            for (int i = 0; i < 4; i++) av[i] = *(const bf16x8*)&As[swz(pixbase + i * 16 + lq, chunk)];
#pragma unroll
            for (int i = 0; i < 4; i++)
#pragma unroll
                for (int j = 0; j < 2; j++)
                    acc[i][j] = __builtin_amdgcn_mfma_f32_16x16x32_bf16(av[i], bv[j], acc[i][j], 0, 0, 0);
        }
        __syncthreads();
    }

    size_t prow = ((size_t)b * HW + h * 128) * 128;
#pragma unroll
    for (int j = 0; j < 2; j++) {
        int oc = ocbase + j * 16 + lq;
        float bias = bdcn[oc];
#pragma unroll
        for (int i = 0; i < 4; i++)
#pragma unroll
            for (int r = 0; r < 4; r++) {
                int pix = pixbase + i * 16 + quad * 4 + r;
                zt[prow + (size_t)pix * 128 + oc] = f2bf(acc[i][j][r] + bias);
            }
    }
}

// ---------------------------------------------------------------------------
// k_conv1: r1 = relu(conv3x3(z) + b1). Halo-once + register-prefetched B.
// 256 thr, 1024 blocks. Block: 64 px x 128 oc. Wave: 64 px x 32 oc.
// ---------------------------------------------------------------------------
__global__ __launch_bounds__(256, 3) void k_conv1(
    const ushort* __restrict__ zt, const ushort* __restrict__ w1B,
    const float* __restrict__ b1, ushort* __restrict__ r1t)
{
    int b, h, px0; bhmap2(b, h, px0);
    const int tid = threadIdx.x;
    const int wid = tid >> 6, lane = tid & 63, lq = lane & 15, quad = lane >> 4;
    const int ocbase = wid * 32, ocg = wid * 2;

    __shared__ __align__(16) ushort Hs[198 * 128];   // 49.5 KB

    stage_halo(Hs, zt, b, h, px0, tid, 256);

    f32x4 acc[4][2];
#pragma unroll
    for (int i = 0; i < 4; i++)
#pragma unroll
        for (int j = 0; j < 2; j++)
#pragma unroll
            for (int r = 0; r < 4; r++) acc[i][j][r] = 0.f;

    bf16x8 bcur[2][4], bnext[2][4];
#pragma unroll
    for (int j = 0; j < 2; j++)
#pragma unroll
        for (int kk = 0; kk < 4; kk++)
            bcur[j][kk] = *(const bf16x8*)(w1B + (size_t)(((ocg + j) * 4 + kk) * 512) + lane * 8);

    __syncthreads();

#pragma unroll
    for (int t9 = 0; t9 < 9; t9++) {
        if (t9 < 8) {
#pragma unroll
            for (int j = 0; j < 2; j++)
#pragma unroll
                for (int kk = 0; kk < 4; kk++)
                    bnext[j][kk] = *(const bf16x8*)(w1B + (size_t)((((t9 + 1) * 8 + ocg + j) * 4 + kk) * 512) + lane * 8);
        }
        const int base = (t9 / 3) * 66 + (t9 % 3);
#pragma unroll
        for (int kk = 0; kk < 4; kk++) {
            int chunk = kk * 4 + quad;
            bf16x8 av[4];
#pragma unroll
            for (int i = 0; i < 4; i++)
                av[i] = *(const bf16x8*)&Hs[swz(base + i * 16 + lq, chunk)];
#pragma unroll
            for (int i = 0; i < 4; i++)
#pragma unroll
                for (int j = 0; j < 2; j++)
                    acc[i][j] = __builtin_amdgcn_mfma_f32_16x16x32_bf16(av[i], bcur[j][kk], acc[i][j], 0, 0, 0);
        }
#pragma unroll
        for (int j = 0; j < 2; j++)
#pragma unroll
            for (int kk = 0; kk < 4; kk++) bcur[j][kk] = bnext[j][kk];
    }

    size_t prow = ((size_t)b * HW + h * 128 + px0) * 128;
#pragma unroll
    for (int j = 0; j < 2; j++) {
        int oc = ocbase + j * 16 + lq;
        float bias = b1[oc];
#pragma unroll
        for (int i = 0; i < 4; i++)
#pragma unroll
            for (int r = 0; r < 4; r++) {
                int pix = i * 16 + quad * 4 + r;
                r1t[prow + (size_t)pix * 128 + oc] = f2bf(fmaxf(acc[i][j][r] + bias, 0.f));
            }
    }
}

// ---------------------------------------------------------------------------
// k_conv2: out = relu(x + (conv3x3(r1)+b2) * sigmoid(10*(clipU-0.5))).
// Halo-once + register-prefetched A(w2); M=oc so NCHW fp32 stores coalesce.
// 256 thr, 1024 blocks. Block: 64 px x 128 oc. Wave: 32 oc x 64 px.
// ---------------------------------------------------------------------------
__global__ __launch_bounds__(256, 3) void k_conv2(
    const ushort* __restrict__ r1t, const ushort* __restrict__ w2B,
    const float* __restrict__ b2, const float* __restrict__ x,
    const float* __restrict__ U, float* __restrict__ out)
{
    int b, h, px0; bhmap2(b, h, px0);
    const int tid = threadIdx.x;
    const int wid = tid >> 6, lane = tid & 63, lq = lane & 15, quad = lane >> 4;
    const int ocbase = wid * 32, ocg = wid * 2;   // M: oc

    __shared__ __align__(16) ushort Hs[198 * 128];   // 49.5 KB

    stage_halo(Hs, r1t, b, h, px0, tid, 256);

    f32x4 acc[2][4];   // [oc group][pixel group]
#pragma unroll
    for (int i = 0; i < 2; i++)
#pragma unroll
        for (int j = 0; j < 4; j++)
#pragma unroll
            for (int r = 0; r < 4; r++) acc[i][j][r] = 0.f;

    bf16x8 acur[2][4], anext[2][4];
#pragma unroll
    for (int i = 0; i < 2; i++)
#pragma unroll
        for (int kk = 0; kk < 4; kk++)
            acur[i][kk] = *(const bf16x8*)(w2B + (size_t)(((ocg + i) * 4 + kk) * 512) + lane * 8);

    __syncthreads();

#pragma unroll
    for (int t9 = 0; t9 < 9; t9++) {
        if (t9 < 8) {
#pragma unroll
            for (int i = 0; i < 2; i++)
#pragma unroll
                for (int kk = 0; kk < 4; kk++)
                    anext[i][kk] = *(const bf16x8*)(w2B + (size_t)((((t9 + 1) * 8 + ocg + i) * 4 + kk) * 512) + lane * 8);
        }
        const int base = (t9 / 3) * 66 + (t9 % 3);
#pragma unroll
        for (int kk = 0; kk < 4; kk++) {
            int chunk = kk * 4 + quad;
            bf16x8 bv[4];
#pragma unroll
            for (int j = 0; j < 4; j++)
                bv[j] = *(const bf16x8*)&Hs[swz(base + j * 16 + lq, chunk)];
#pragma unroll
            for (int i = 0; i < 2; i++)
#pragma unroll
                for (int j = 0; j < 4; j++)
                    acc[i][j] = __builtin_amdgcn_mfma_f32_16x16x32_bf16(acur[i][kk], bv[j], acc[i][j], 0, 0, 0);
        }
#pragma unroll
        for (int i = 0; i < 2; i++)
#pragma unroll
            for (int kk = 0; kk < 4; kk++) acur[i][kk] = anext[i][kk];
    }

#pragma unroll
    for (int j = 0; j < 4; j++) {
        int pix = j * 16 + lq;                       // local 0..63
        float u = U[(size_t)b * HW + h * 128 + px0 + pix];
        u = fminf(fmaxf(u, 0.f), 1.f);
        float g = 1.f / (1.f + __expf(-10.f * (u - 0.5f)));
#pragma unroll
        for (int i = 0; i < 2; i++) {
            f32x4 b4 = *(const f32x4*)&b2[ocbase + i * 16 + quad * 4];
#pragma unroll
            for (int r = 0; r < 4; r++) {
                int oc = ocbase + i * 16 + quad * 4 + r;
                size_t idx = ((size_t)(b * 128 + oc)) * HW + h * 128 + px0 + pix;
                float v = acc[i][j][r] + b4[r];
                out[idx] = fmaxf(x[idx] + v * g, 0.f);
            }
        }
    }
}

// ---------------------------------------------------------------------------
extern "C" void kernel_launch(void* const* d_in, const int* in_sizes, int n_in,
                              void* d_out, int out_size, void* d_ws, size_t ws_size,
                              hipStream_t stream)
{
    const float* x     = (const float*)d_in[0];
    const float* U     = (const float*)d_in[1];
    const float* w_om  = (const float*)d_in[2];
    const float* b_om  = (const float*)d_in[3];
    const float* w_dcn = (const float*)d_in[4];
    const float* b_dcn = (const float*)d_in[5];
    const float* w1    = (const float*)d_in[6];
    const float* b1    = (const float*)d_in[7];
    const float* w2    = (const float*)d_in[8];
    const float* b2    = (const float*)d_in[9];
    float* out = (float*)d_out;

    char* p = (char*)d_ws;
    ushort* xt   = (ushort*)p; p += (size_t)4 * HW * 128 * 2;   // 16.78 MB
    ushort* zt   = (ushort*)p; p += (size_t)4 * HW * 128 * 2;
    ushort* r1t  = (ushort*)p; p += (size_t)4 * HW * 128 * 2;
    float*  omt  = (float*)p;  p += (size_t)4 * HW * 32 * 4;    // 8.39 MB
    ushort* wdt  = (ushort*)p; p += 147456 * 2;
    ushort* w1B  = (ushort*)p; p += 147456 * 2;
    ushort* w2B  = (ushort*)p; p += 147456 * 2;
    ushort* womB = (ushort*)p; p += 36864 * 2;
    float*  womu = (float*)p;  p += 288 * 4;

    prep_w<<<576, 256, 0, stream>>>(w_dcn, w1, w2, w_om, wdt, w1B, w2B, womB, womu);
    prep_xt<<<dim3(128, 4), 256, 0, stream>>>(x, xt);
    k_om<<<1024, 256, 0, stream>>>(xt, U, womB, womu, b_om, omt);
    k_dcn<<<dim3(128, 4), 512, 0, stream>>>(xt, omt, wdt, b_dcn, zt);
    k_conv1<<<1024, 256, 0, stream>>>(zt, w1B, b1, r1t);
    k_conv2<<<1024, 256, 0, stream>>>(r1t, w2B, b2, x, U, out);
}